// Round 1
// baseline (1976.262 us; speedup 1.0000x reference)
//
#include <hip/hip_runtime.h>
#include <hip/hip_bf16.h>

#define HDIM 128
#define NSTAGE 7

typedef __bf16 bf16x8 __attribute__((ext_vector_type(8)));
typedef __bf16 bf16x4 __attribute__((ext_vector_type(4)));
typedef float floatx16 __attribute__((ext_vector_type(16)));
typedef float floatx4 __attribute__((ext_vector_type(4)));

__device__ __forceinline__ float silu_f(float x) {
    // x * sigmoid(x); fast hw exp + rcp. Large |x| limits are correct.
    return x * __builtin_amdgcn_rcpf(1.0f + __expf(-x));
}

// Convert the 7 weight matrices (W1[0..2], W2[0..2], Wlin interleaved as
// stage order W1[0],W2[0],W1[1],W2[1],W1[2],W2[2],Wlin) to bf16 in d_ws,
// with a 16B-chunk XOR swizzle: element [m][k] -> m*128 + ((k>>3)^(m&7))*8 + (k&7).
// This makes wave-wide ds_read_b128 of W rows bank-uniform (8 dwords/bank).
__global__ void convert_weights(const float* __restrict__ W1,
                                const float* __restrict__ W2,
                                const float* __restrict__ Wlin,
                                __bf16* __restrict__ dst) {
    int idx = blockIdx.x * blockDim.x + threadIdx.x;
    if (idx >= NSTAGE * HDIM * HDIM) return;
    int s    = idx >> 14;          // stage 0..6
    int rem  = idx & 16383;
    int mrow = rem >> 7;           // out-feature row
    int k    = rem & 127;          // in-feature col
    const float* src;
    if (s == 6) src = Wlin;
    else {
        int l = s >> 1;
        src = ((s & 1) ? W2 : W1) + l * HDIM * HDIM;
    }
    float v = src[mrow * HDIM + k];
    int dsti = (s << 14) + (mrow << 7) + ((((k >> 3) ^ (mrow & 7)) << 3) | (k & 7));
    dst[dsti] = (__bf16)v;
}

// Fused: for l in 0..2 { h = silu(X)@W1[l]^T + b1; X += silu(h)@W2[l]^T + b2 }
// then Y = silu(X@Wlin^T + blin); atomically scatter Y into out[tgt[e]].
// One wave owns 32 edges. All matmuls computed transposed:
//   D[feature][edge] = W[feature][k] * act[edge][k]
// using mfma_f32_32x32x16_bf16 with A = W-frag, B = act-frag.
// C/D layout: edge = lane&31, feature = mb*32 + (reg&3) + 8*(reg>>2) + 4*(lane>>5)
//   -> each reg-quad holds 4 consecutive features of one edge (vectorizable).
// A/B layout: row/col index = lane&31, k = (lane>>5)*8 + j (8 contiguous bf16 = b128).
__global__ __launch_bounds__(256, 2) void fused_mlp_scatter(
    const float* __restrict__ m,        // [E][128] fp32
    const int* __restrict__ tgt,        // edge_index row 1, [E] int32
    const __bf16* __restrict__ wmats,   // [7][128][128] bf16, swizzled
    const float* __restrict__ b1,       // [3][128]
    const float* __restrict__ b2,       // [3][128]
    const float* __restrict__ blin,     // [128]
    float* __restrict__ out,            // [N][128] fp32 (zeroed)
    int E, int ntiles)
{
    __shared__ __bf16 wlds[HDIM * HDIM];        // 32 KB, swizzled like wmats
    __shared__ __bf16 actbuf[4 * 32 * 136];     // 34 KB; stride 136 (=128+8) per edge-row

    const int tid  = threadIdx.x;
    const int w    = tid >> 6;
    const int lane = tid & 63;
    const int l31  = lane & 31;
    const int half = lane >> 5;

    const int tile    = blockIdx.x * 4 + w;
    const bool activeW = (tile < ntiles);
    int eidx = tile * 32 + l31;
    const bool evalid = activeW && (eidx < E);
    if (!activeW || eidx >= E) eidx = 0;  // clamp; guarded at emit time

    // Residual stream X in registers, fp32: X[mb][q] = feats mb*32+q*8+half*4 .. +3
    floatx4 X[4][4];
    __bf16* actw = &actbuf[(w * 32 + l31) * 136];

    if (activeW) {
        const float* mrow = m + (size_t)eidx * HDIM;
        for (int mb = 0; mb < 4; ++mb)
            for (int q = 0; q < 4; ++q) {
                int f0 = mb * 32 + q * 8 + half * 4;
                X[mb][q] = *(const floatx4*)(mrow + f0);
            }
        // stage-0 operand: silu(X) in bf16, [edge][feature] contiguous
        for (int mb = 0; mb < 4; ++mb)
            for (int q = 0; q < 4; ++q) {
                int f0 = mb * 32 + q * 8 + half * 4;
                bf16x4 v;
                for (int j = 0; j < 4; ++j) v[j] = (__bf16)silu_f(X[mb][q][j]);
                *(bf16x4*)(actw + f0) = v;
            }
    }

    for (int s = 0; s < NSTAGE; ++s) {
        __syncthreads();   // all waves done reading previous wlds
        // cooperative W stage: 32 KB, all 256 threads, b128 both sides
        {
            const __bf16* wsrc = wmats + (s << 14);
            for (int i = 0; i < 8; ++i) {
                int off = i * 2048 + tid * 8;   // bf16 elements
                *(bf16x8*)(&wlds[off]) = *(const bf16x8*)(wsrc + off);
            }
        }
        __syncthreads();
        if (!activeW) continue;   // still hits top barrier next iter — uniform count

        floatx16 acc[4];
        for (int mb = 0; mb < 4; ++mb)
            for (int r = 0; r < 16; ++r) acc[mb][r] = 0.0f;

        for (int ks = 0; ks < 8; ++ks) {
            bf16x8 bfrag = *(const bf16x8*)(actw + ks * 16 + half * 8);
            int krow = ks * 2 + half;   // 16B chunk index within a W row
            for (int mb = 0; mb < 4; ++mb) {
                int mr = mb * 32 + l31;
                bf16x8 afrag = *(const bf16x8*)(&wlds[(mr << 7) + ((krow ^ (mr & 7)) << 3)]);
                acc[mb] = __builtin_amdgcn_mfma_f32_32x32x16_bf16(afrag, bfrag, acc[mb], 0, 0, 0);
            }
        }

        if (s == 6) {
            // Y = silu(acc + blin); scatter-add into out[tgt[e]]
            if (evalid) {
                int node = tgt[eidx];
                float* op = out + (size_t)node * HDIM;
                for (int mb = 0; mb < 4; ++mb)
                    for (int q = 0; q < 4; ++q) {
                        int f0 = mb * 32 + q * 8 + half * 4;
                        floatx4 bv = *(const floatx4*)(blin + f0);
                        for (int j = 0; j < 4; ++j) {
                            float v = silu_f(acc[mb][q * 4 + j] + bv[j]);
                            unsafeAtomicAdd(op + f0 + j, v);
                        }
                    }
            }
        } else if ((s & 1) == 0) {
            // mm1: h = acc + b1; emit silu(h) as next operand
            const float* bias = b1 + (s >> 1) * HDIM;
            for (int mb = 0; mb < 4; ++mb)
                for (int q = 0; q < 4; ++q) {
                    int f0 = mb * 32 + q * 8 + half * 4;
                    floatx4 bv = *(const floatx4*)(bias + f0);
                    bf16x4 hv;
                    for (int j = 0; j < 4; ++j)
                        hv[j] = (__bf16)silu_f(acc[mb][q * 4 + j] + bv[j]);
                    *(bf16x4*)(actw + f0) = hv;
                }
        } else {
            // mm2: X += acc + b2; emit silu(X) (layers 0,1) or plain X (pre-Wlin)
            const float* bias = b2 + (s >> 1) * HDIM;
            for (int mb = 0; mb < 4; ++mb)
                for (int q = 0; q < 4; ++q) {
                    int f0 = mb * 32 + q * 8 + half * 4;
                    floatx4 bv = *(const floatx4*)(bias + f0);
                    bf16x4 xv;
                    for (int j = 0; j < 4; ++j) {
                        float nx = X[mb][q][j] + acc[mb][q * 4 + j] + bv[j];
                        X[mb][q][j] = nx;
                        xv[j] = (__bf16)((s == 5) ? nx : silu_f(nx));
                    }
                    *(bf16x4*)(actw + f0) = xv;
                }
        }
    }
}

extern "C" void kernel_launch(void* const* d_in, const int* in_sizes, int n_in,
                              void* d_out, int out_size, void* d_ws, size_t ws_size,
                              hipStream_t stream) {
    const float* m      = (const float*)d_in[0];
    const int* edge_idx = (const int*)d_in[1];
    const float* W1     = (const float*)d_in[3];
    const float* b1     = (const float*)d_in[4];
    const float* W2     = (const float*)d_in[5];
    const float* b2     = (const float*)d_in[6];
    const float* Wlin   = (const float*)d_in[7];
    const float* blin   = (const float*)d_in[8];

    int E = in_sizes[0] / HDIM;
    const int* tgt = edge_idx + E;            // edge_index[1]
    __bf16* wbf = (__bf16*)d_ws;              // 7*128*128 bf16 = 224 KB

    hipMemsetAsync(d_out, 0, (size_t)out_size * sizeof(float), stream);
    convert_weights<<<(NSTAGE * HDIM * HDIM + 255) / 256, 256, 0, stream>>>(W1, W2, Wlin, wbf);

    int ntiles  = (E + 31) / 32;
    int nblocks = (ntiles + 3) / 4;
    fused_mlp_scatter<<<nblocks, 256, 0, stream>>>(m, tgt, wbf, b1, b2, blin,
                                                   (float*)d_out, E, ntiles);
}

// Round 2
// 798.466 us; speedup vs baseline: 2.4751x; 2.4751x over previous
//
#include <hip/hip_runtime.h>
#include <hip/hip_bf16.h>

#define HDIM 128
#define NSTAGE 7

typedef __bf16 bf16x8 __attribute__((ext_vector_type(8)));
typedef __bf16 bf16x4 __attribute__((ext_vector_type(4)));
typedef float floatx16 __attribute__((ext_vector_type(16)));
typedef float floatx4 __attribute__((ext_vector_type(4)));

__device__ __forceinline__ float silu_f(float x) {
    return x * __builtin_amdgcn_rcpf(1.0f + __expf(-x));
}

// Weights -> bf16 in d_ws, stage order W1[0],W2[0],W1[1],W2[1],W1[2],W2[2],Wlin.
// XOR swizzle on 16B chunks: [m][k] -> m*128 + ((k>>3)^(m&7))*8 + (k&7), so
// wave-wide ds_read_b128 of W fragments is bank-uniform.
__global__ void convert_weights(const float* __restrict__ W1,
                                const float* __restrict__ W2,
                                const float* __restrict__ Wlin,
                                __bf16* __restrict__ dst) {
    int idx = blockIdx.x * blockDim.x + threadIdx.x;
    if (idx >= NSTAGE * HDIM * HDIM) return;
    int s    = idx >> 14;
    int rem  = idx & 16383;
    int mrow = rem >> 7;
    int k    = rem & 127;
    const float* src;
    if (s == 6) src = Wlin;
    else {
        int l = s >> 1;
        src = ((s & 1) ? W2 : W1) + l * HDIM * HDIM;
    }
    float v = src[mrow * HDIM + k];
    int dsti = (s << 14) + (mrow << 7) + ((((k >> 3) ^ (mrow & 7)) << 3) | (k & 7));
    dst[dsti] = (__bf16)v;
}

// One wave owns 32 edges end-to-end; residual X in fp32 registers.
// All matmuls transposed: D[feat][edge] = W[feat][k]*act[edge][k] via
// mfma_f32_32x32x16_bf16. C/D: edge=lane&31, feat=mb*32+(reg&3)+8*(reg>>2)+4*(lane>>5).
// Activation LDS layout per edge-row (stride 136 bf16) with 16B-granule
// rotation: element [e][f] at e*136 + (((f>>4)+e)&7)*16 + (f&15)
//   -> b128 reads: bank-group = (3e+2gr+half) mod 8, conflict-free
//   -> b64 writes: bank = (12e+8gr+c) mod 32, conflict-free.
// Epilogue: Y transposed through LDS (f32, stride 132) so the scatter does
// 64-consecutive-dword atomic instructions (4 cache lines, not 64).
__global__ __launch_bounds__(256, 2) void fused_mlp_scatter(
    const float* __restrict__ m,
    const int* __restrict__ tgt,
    const __bf16* __restrict__ wmats,
    const float* __restrict__ b1,
    const float* __restrict__ b2,
    const float* __restrict__ blin,
    float* __restrict__ out,
    int E, int ntiles)
{
    __shared__ __align__(16) char smem[67584];
    __bf16* wlds   = (__bf16*)smem;                  // 32 KB
    __bf16* actAll = (__bf16*)(smem + 32768);        // 4*32*136 bf16 = 34816 B
    float*  ybuf   = (float*)smem;                   // 4*32*132 f32 = 67584 B (overlay)

    const int tid  = threadIdx.x;
    const int w    = tid >> 6;
    const int lane = tid & 63;
    const int l31  = lane & 31;
    const int half = lane >> 5;

    const int tile    = blockIdx.x * 4 + w;
    const bool activeW = (tile < ntiles);
    int eidx = tile * 32 + l31;
    const bool evalid = activeW && (eidx < E);
    if (!evalid) eidx = 0;

    int mynode = 0;
    if (evalid) mynode = tgt[eidx];

    floatx4 X[4][4];
    floatx4 Yv[4][4];
    __bf16* actw = actAll + (w * 32 + l31) * 136;

    // swizzled offset within this edge-row for feature f (f multiple of 4)
    #define ACT_OFF(f) (((((((f) >> 4) + l31) & 7)) << 4) | ((f) & 15))

    if (activeW) {
        const float* mrow = m + (size_t)eidx * HDIM;
        for (int mb = 0; mb < 4; ++mb)
            for (int q = 0; q < 4; ++q) {
                int f0 = mb * 32 + q * 8 + half * 4;
                X[mb][q] = *(const floatx4*)(mrow + f0);
            }
        for (int mb = 0; mb < 4; ++mb)
            for (int q = 0; q < 4; ++q) {
                int f0 = mb * 32 + q * 8 + half * 4;
                bf16x4 v;
                for (int j = 0; j < 4; ++j) v[j] = (__bf16)silu_f(X[mb][q][j]);
                *(bf16x4*)(actw + ACT_OFF(f0)) = v;
            }
    }

    for (int s = 0; s < NSTAGE; ++s) {
        __syncthreads();
        {
            const __bf16* wsrc = wmats + (s << 14);
            for (int i = 0; i < 8; ++i) {
                int off = i * 2048 + tid * 8;
                *(bf16x8*)(&wlds[off]) = *(const bf16x8*)(wsrc + off);
            }
        }
        __syncthreads();
        if (!activeW) continue;

        floatx16 acc[4];
        for (int mb = 0; mb < 4; ++mb)
            for (int r = 0; r < 16; ++r) acc[mb][r] = 0.0f;

        for (int ks = 0; ks < 8; ++ks) {
            bf16x8 bfrag = *(const bf16x8*)(actw + ((((ks + l31) & 7) << 4) + half * 8));
            int krow = ks * 2 + half;
            for (int mb = 0; mb < 4; ++mb) {
                int mr = mb * 32 + l31;
                bf16x8 afrag = *(const bf16x8*)(&wlds[(mr << 7) + ((krow ^ (mr & 7)) << 3)]);
                acc[mb] = __builtin_amdgcn_mfma_f32_32x32x16_bf16(afrag, bfrag, acc[mb], 0, 0, 0);
            }
        }

        if (s == 6) {
            for (int mb = 0; mb < 4; ++mb)
                for (int q = 0; q < 4; ++q) {
                    int f0 = mb * 32 + q * 8 + half * 4;
                    floatx4 bv = *(const floatx4*)(blin + f0);
                    for (int j = 0; j < 4; ++j)
                        Yv[mb][q][j] = silu_f(acc[mb][q * 4 + j] + bv[j]);
                }
        } else if ((s & 1) == 0) {
            const float* bias = b1 + (s >> 1) * HDIM;
            for (int mb = 0; mb < 4; ++mb)
                for (int q = 0; q < 4; ++q) {
                    int f0 = mb * 32 + q * 8 + half * 4;
                    floatx4 bv = *(const floatx4*)(bias + f0);
                    bf16x4 hv;
                    for (int j = 0; j < 4; ++j)
                        hv[j] = (__bf16)silu_f(acc[mb][q * 4 + j] + bv[j]);
                    *(bf16x4*)(actw + ACT_OFF(f0)) = hv;
                }
        } else {
            const float* bias = b2 + (s >> 1) * HDIM;
            for (int mb = 0; mb < 4; ++mb)
                for (int q = 0; q < 4; ++q) {
                    int f0 = mb * 32 + q * 8 + half * 4;
                    floatx4 bv = *(const floatx4*)(bias + f0);
                    bf16x4 xv;
                    for (int j = 0; j < 4; ++j) {
                        float nx = X[mb][q][j] + acc[mb][q * 4 + j] + bv[j];
                        X[mb][q][j] = nx;
                        xv[j] = (__bf16)((s == 5) ? nx : silu_f(nx));
                    }
                    *(bf16x4*)(actw + ACT_OFF(f0)) = xv;
                }
        }
    }

    // ---- epilogue: transpose Y through LDS, then line-coalesced scatter ----
    __syncthreads();   // everyone done reading wlds/actAll
    if (activeW) {
        float* yrow = ybuf + (w * 32 + l31) * 132;
        for (int mb = 0; mb < 4; ++mb)
            for (int q = 0; q < 4; ++q) {
                int f0 = mb * 32 + q * 8 + half * 4;
                *(floatx4*)(yrow + f0) = Yv[mb][q];
            }
    }
    __syncthreads();
    if (activeW) {
        const float* yb = ybuf + w * 32 * 132;
        const int ebase = tile * 32;
        for (int e = 0; e < 32; ++e) {
            if (ebase + e >= E) break;
            int node = __builtin_amdgcn_readlane(mynode, e);
            float v0 = yb[e * 132 + lane];
            float v1 = yb[e * 132 + 64 + lane];
            float* op = out + (size_t)node * HDIM;
            unsafeAtomicAdd(op + lane, v0);
            unsafeAtomicAdd(op + 64 + lane, v1);
        }
    }
    #undef ACT_OFF
}

extern "C" void kernel_launch(void* const* d_in, const int* in_sizes, int n_in,
                              void* d_out, int out_size, void* d_ws, size_t ws_size,
                              hipStream_t stream) {
    const float* m      = (const float*)d_in[0];
    const int* edge_idx = (const int*)d_in[1];
    const float* W1     = (const float*)d_in[3];
    const float* b1     = (const float*)d_in[4];
    const float* W2     = (const float*)d_in[5];
    const float* b2     = (const float*)d_in[6];
    const float* Wlin   = (const float*)d_in[7];
    const float* blin   = (const float*)d_in[8];

    int E = in_sizes[0] / HDIM;
    const int* tgt = edge_idx + E;
    __bf16* wbf = (__bf16*)d_ws;

    hipMemsetAsync(d_out, 0, (size_t)out_size * sizeof(float), stream);
    convert_weights<<<(NSTAGE * HDIM * HDIM + 255) / 256, 256, 0, stream>>>(W1, W2, Wlin, wbf);

    int ntiles  = (E + 31) / 32;
    int nblocks = (ntiles + 3) / 4;
    fused_mlp_scatter<<<nblocks, 256, 0, stream>>>(m, tgt, wbf, b1, b2, blin,
                                                   (float*)d_out, E, ntiles);
}